// Round 4
// baseline (22307.193 us; speedup 1.0000x reference)
//
#include <hip/hip_runtime.h>
#include <cmath>

#define BB 64
#define TT 512
#define II 256
#define HH 1024
#define OO 512
#define NWG 256

// LDS weight layout (float offsets)
#define O_WHH0 0
#define O_WIH1 4096
#define O_WHH1 8192
#define O_WIH0 12288
#define WL_FLOATS 13312   // 53 KB weights + 8 KB Ps = 61 KB LDS

__device__ __forceinline__ float dot4(float4 a, float4 b) {
    return a.x * b.x + a.y * b.y + a.z * b.z + a.w * b.w;
}

// Persistent pipelined 2-layer RNN. One WG per CU; WG g owns rows 4g..4g+3 of
// BOTH layers. Launch-step t computes h1_t (layer 0) and h2_{t-1} (layer 1);
// both consume the SAME h1_{t-1} vector, so one h-load feeds 8 weight rows.
// h stored transposed: hT4[k>>2][b][k&3]; 256 KB per buffer, ping-pong x2 x2.
__global__ __launch_bounds__(1024) void rnn_persist(
    const float* __restrict__ x,
    const float* __restrict__ Wih0, const float* __restrict__ Whh0,
    const float* __restrict__ bih0, const float* __restrict__ bhh0,
    const float* __restrict__ Wih1, const float* __restrict__ Whh1,
    const float* __restrict__ bih1, const float* __restrict__ bhh1,
    const float* __restrict__ Wfc,  const float* __restrict__ bfc,
    float* __restrict__ out, float* __restrict__ ws)
{
    __shared__ float Wl[WL_FLOATS];
    __shared__ float Ps[16][64][2];

    const int g    = blockIdx.x;
    const int tid  = threadIdx.x;
    const int w    = tid >> 6;     // wave 0..15 -> K-slice
    const int lane = tid & 63;     // batch index

    unsigned* bar = (unsigned*)ws;
    unsigned* gen = ((unsigned*)ws) + 1;
    float* h1a = ws + 64;
    float* h1b = h1a + 65536;
    float* h2a = h1b + 65536;
    float* h2b = h2a + 65536;      // total ws use: 1 MB + 256 B

    // ---- stage this WG's weight rows into LDS (once) ----
    {
        float4* d = (float4*)Wl;
        d[O_WHH0 / 4 + tid] = ((const float4*)(Whh0 + (size_t)(4 * g) * HH))[tid];
        d[O_WIH1 / 4 + tid] = ((const float4*)(Wih1 + (size_t)(4 * g) * HH))[tid];
        d[O_WHH1 / 4 + tid] = ((const float4*)(Whh1 + (size_t)(4 * g) * HH))[tid];
        if (tid < 256)
            d[O_WIH0 / 4 + tid] = ((const float4*)(Wih0 + (size_t)(4 * g) * II))[tid];
    }
    __syncthreads();

    unsigned gen_target = 0;

    for (int t = 0; t <= TT; ++t) {
        float acc[8] = {0.f, 0.f, 0.f, 0.f, 0.f, 0.f, 0.f, 0.f};

        // ---- x-part of layer 0 (K=256): lane = k-chunk, butterfly reduce ----
        if (t < TT) {
            float4 wx0 = *(const float4*)&Wl[O_WIH0 + 0 * 256 + lane * 4];
            float4 wx1 = *(const float4*)&Wl[O_WIH0 + 1 * 256 + lane * 4];
            float4 wx2 = *(const float4*)&Wl[O_WIH0 + 2 * 256 + lane * 4];
            float4 wx3 = *(const float4*)&Wl[O_WIH0 + 3 * 256 + lane * 4];
            #pragma unroll
            for (int i = 0; i < 4; ++i) {
                const int b = (w << 2) | i;
                const float4 xv = *(const float4*)(x + ((size_t)b * TT + t) * II + lane * 4);
                float p0 = dot4(xv, wx0), p1 = dot4(xv, wx1);
                float p2 = dot4(xv, wx2), p3 = dot4(xv, wx3);
                #pragma unroll
                for (int m = 32; m >= 1; m >>= 1) {
                    p0 += __shfl_xor(p0, m, 64);
                    p1 += __shfl_xor(p1, m, 64);
                    p2 += __shfl_xor(p2, m, 64);
                    p3 += __shfl_xor(p3, m, 64);
                }
                if (lane == b) {
                    acc[0] += p0; acc[1] += p1; acc[2] += p2; acc[3] += p3;
                }
            }
        }

        // ---- h1_{t-1} part: feeds L0 rows (Whh0) AND L1 rows (Wih1) ----
        if (t >= 1) {
            const float* h1r = ((t - 1) & 1) ? h1b : h1a;
            if (t < TT) {
                #pragma unroll 4
                for (int k4 = w * 16; k4 < w * 16 + 16; ++k4) {
                    const float4 hv = *(const float4*)(h1r + k4 * 256 + lane * 4);
                    #pragma unroll
                    for (int c = 0; c < 4; ++c) {
                        acc[c]     += dot4(hv, *(const float4*)&Wl[O_WHH0 + c * 1024 + k4 * 4]);
                        acc[4 + c] += dot4(hv, *(const float4*)&Wl[O_WIH1 + c * 1024 + k4 * 4]);
                    }
                }
            } else {
                #pragma unroll 4
                for (int k4 = w * 16; k4 < w * 16 + 16; ++k4) {
                    const float4 hv = *(const float4*)(h1r + k4 * 256 + lane * 4);
                    #pragma unroll
                    for (int c = 0; c < 4; ++c)
                        acc[4 + c] += dot4(hv, *(const float4*)&Wl[O_WIH1 + c * 1024 + k4 * 4]);
                }
            }
        }

        // ---- h2_{t-2} part: L1 recurrent (Whh1) ----
        if (t >= 2) {
            const float* h2r = ((t - 2) & 1) ? h2b : h2a;
            #pragma unroll 4
            for (int k4 = w * 16; k4 < w * 16 + 16; ++k4) {
                const float4 hv = *(const float4*)(h2r + k4 * 256 + lane * 4);
                #pragma unroll
                for (int c = 0; c < 4; ++c)
                    acc[4 + c] += dot4(hv, *(const float4*)&Wl[O_WHH1 + c * 1024 + k4 * 4]);
            }
        }

        // ---- phased deterministic cross-wave reduce + epilogue ----
        #pragma unroll
        for (int p = 0; p < 4; ++p) {
            __syncthreads();
            Ps[w][lane][0] = acc[2 * p];
            Ps[w][lane][1] = acc[2 * p + 1];
            __syncthreads();
            if (w < 2) {
                const int r = 2 * p + w;   // 0..7
                float s = 0.f;
                #pragma unroll
                for (int j = 0; j < 16; ++j) s += Ps[j][lane][w];
                if (r < 4) {
                    if (t < TT) {
                        const int R = 4 * g + r;
                        s += bih0[R] + bhh0[R];
                        s = tanhf(s);
                        float* hw = (t & 1) ? h1b : h1a;
                        hw[(size_t)g * 256 + lane * 4 + r] = s;
                    }
                } else {
                    if (t >= 1) {
                        const int R = 4 * g + (r - 4);
                        s += bih1[R] + bhh1[R];
                        s = tanhf(s);
                        float* hw = ((t - 1) & 1) ? h2b : h2a;
                        hw[(size_t)g * 256 + lane * 4 + (r - 4)] = s;
                    }
                }
            }
        }

        // ---- grid barrier (sense via generation counter) ----
        __syncthreads();
        ++gen_target;
        if (tid == 0) {
            __threadfence();
            unsigned a = __hip_atomic_fetch_add(bar, 1u, __ATOMIC_ACQ_REL,
                                                __HIP_MEMORY_SCOPE_AGENT);
            if (a == NWG - 1) {
                __hip_atomic_store(bar, 0u, __ATOMIC_RELAXED, __HIP_MEMORY_SCOPE_AGENT);
                __hip_atomic_store(gen, gen_target, __ATOMIC_RELEASE,
                                   __HIP_MEMORY_SCOPE_AGENT);
            } else {
                while (__hip_atomic_load(gen, __ATOMIC_ACQUIRE,
                                         __HIP_MEMORY_SCOPE_AGENT) < gen_target)
                    __builtin_amdgcn_s_sleep(2);
            }
        }
        __syncthreads();
    }

    // ---- FC: out[b][2g+w'] for w'=0,1 ; h2_511 is in slot 1 (h2b) ----
    if (tid < 512)
        ((float4*)Wl)[tid] = ((const float4*)(Wfc + (size_t)(2 * g) * HH))[tid];
    __syncthreads();

    float a2_0 = 0.f, a2_1 = 0.f;
    #pragma unroll 4
    for (int k4 = w * 16; k4 < w * 16 + 16; ++k4) {
        const float4 hv = *(const float4*)(h2b + k4 * 256 + lane * 4);
        a2_0 += dot4(hv, *(const float4*)&Wl[0 * 1024 + k4 * 4]);
        a2_1 += dot4(hv, *(const float4*)&Wl[1 * 1024 + k4 * 4]);
    }
    __syncthreads();
    Ps[w][lane][0] = a2_0;
    Ps[w][lane][1] = a2_1;
    __syncthreads();
    if (w < 2) {
        float s = 0.f;
        #pragma unroll
        for (int j = 0; j < 16; ++j) s += Ps[j][lane][w];
        s += bfc[2 * g + w];
        out[(size_t)lane * OO + 2 * g + w] = s;
    }
}

extern "C" void kernel_launch(void* const* d_in, const int* in_sizes, int n_in,
                              void* d_out, int out_size, void* d_ws, size_t ws_size,
                              hipStream_t stream) {
    const float* x    = (const float*)d_in[0];
    const float* Wih0 = (const float*)d_in[1];
    const float* Whh0 = (const float*)d_in[2];
    const float* bih0 = (const float*)d_in[3];
    const float* bhh0 = (const float*)d_in[4];
    const float* Wih1 = (const float*)d_in[5];
    const float* Whh1 = (const float*)d_in[6];
    const float* bih1 = (const float*)d_in[7];
    const float* bhh1 = (const float*)d_in[8];
    const float* Wfc  = (const float*)d_in[9];
    const float* bfc  = (const float*)d_in[10];
    float* out = (float*)d_out;
    float* ws  = (float*)d_ws;

    // zero the barrier state (bar, gen) every call — replay-safe
    hipMemsetAsync(d_ws, 0, 8, stream);

    void* args[] = { (void*)&x,
                     (void*)&Wih0, (void*)&Whh0, (void*)&bih0, (void*)&bhh0,
                     (void*)&Wih1, (void*)&Whh1, (void*)&bih1, (void*)&bhh1,
                     (void*)&Wfc,  (void*)&bfc,  (void*)&out,  (void*)&ws };
    hipLaunchCooperativeKernel((void*)rnn_persist, dim3(NWG), dim3(1024),
                               args, 0, stream);
}

// Round 5
// 11028.371 us; speedup vs baseline: 2.0227x; 2.0227x over previous
//
#include <hip/hip_runtime.h>
#include <cmath>

#define BB 64
#define TT 512
#define II 256
#define HH 1024
#define OO 512

typedef short bf8 __attribute__((ext_vector_type(8)));    // 8 bf16 vals
typedef float f32x4 __attribute__((ext_vector_type(4)));

#define MFMA(a, b, c) __builtin_amdgcn_mfma_f32_16x16x32_bf16((a), (b), (c), 0, 0, 0)

__device__ __forceinline__ unsigned short f2bf(float f) {
    unsigned u = __float_as_uint(f);
    return (unsigned short)((u + 0x7fffu + ((u >> 16) & 1u)) >> 16);
}
__device__ __forceinline__ float bf2f(unsigned short h) {
    return __uint_as_float((unsigned)h << 16);
}
__device__ __forceinline__ void split8(const float* v, bf8& hi, bf8& lo) {
#pragma unroll
    for (int j = 0; j < 8; ++j) {
        unsigned short h = f2bf(v[j]);
        float r = v[j] - bf2f(h);
        hi[j] = (short)h;
        lo[j] = (short)f2bf(r);
    }
}

// h fragment-packed layout per (layer, parity, group): 32 K-chunks x 64 lanes x
// (8 bf16 hi [16B] + 8 bf16 lo [16B]) = 64 KB. Element h[b][k] lives at
// chunk k>>5, lane (b&15) + 16*((k&31)>>3), byte j=(k&7): hi at j*2, lo at j*2+16.
//
// Grid: 256 WGs x 512 thr. group = blockIdx&3 (batches group*16..+15),
// cu = blockIdx>>2 (rows cu*16..+15 of both layers).
// Waves 0-3: L0 tile (x K-slice 64 + h1 K-slice 256 each).
// Waves 4-7: L1 tile (h1 K-slice 256 + h2 K-slice 256 each).
__global__ __launch_bounds__(512, 2) void rnn_mfma(
    const float* __restrict__ x,
    const float* __restrict__ Wih0, const float* __restrict__ Whh0,
    const float* __restrict__ bih0, const float* __restrict__ bhh0,
    const float* __restrict__ Wih1, const float* __restrict__ Whh1,
    const float* __restrict__ bih1, const float* __restrict__ bhh1,
    const float* __restrict__ Wfc,  const float* __restrict__ bfc,
    float* __restrict__ out, float* __restrict__ ws)
{
    const int tid  = threadIdx.x;
    const int w    = tid >> 6;      // wave 0..7
    const int lane = tid & 63;
    const int col  = lane & 15;     // mfma row/col index within fragment
    const int kg   = lane >> 4;     // k-group 0..3
    const int grp  = blockIdx.x & 3;
    const int cu   = blockIdx.x >> 2;
    const int rb   = cu * 16;       // row block
    const int b0   = grp * 16;      // batch block

    __shared__ float shmem[4224];   // Ps [8][16][17] = 2176 | Wlds 2048

    char* wsB = (char*)ws;
    unsigned* bar  = (unsigned*)(wsB + (size_t)grp * 128);
    unsigned* gen  = bar + 1;
    unsigned* gbar = (unsigned*)(wsB + 512);
    unsigned* ggen = gbar + 1;
    char* h1base = wsB + 1024;
    char* h2base = h1base + 8 * 65536;

    // ---- preload weight B-fragments into registers (once) ----
    bf8 wreg[32];
    if (w < 4) {
        #pragma unroll
        for (int c = 0; c < 2; ++c) {
            const float* p = Wih0 + (size_t)(rb + col) * II + (w * 64 + c * 32 + kg * 8);
            float v[8];
            *(float4*)v       = *(const float4*)p;
            *(float4*)(v + 4) = *(const float4*)(p + 4);
            split8(v, wreg[2 * c], wreg[2 * c + 1]);
        }
        #pragma unroll
        for (int c = 0; c < 8; ++c) {
            const float* p = Whh0 + (size_t)(rb + col) * HH + (w * 256 + c * 32 + kg * 8);
            float v[8];
            *(float4*)v       = *(const float4*)p;
            *(float4*)(v + 4) = *(const float4*)(p + 4);
            split8(v, wreg[4 + 2 * c], wreg[5 + 2 * c]);
        }
    } else {
        const int w4 = w - 4;
        #pragma unroll
        for (int c = 0; c < 8; ++c) {
            const float* p = Wih1 + (size_t)(rb + col) * HH + (w4 * 256 + c * 32 + kg * 8);
            float v[8];
            *(float4*)v       = *(const float4*)p;
            *(float4*)(v + 4) = *(const float4*)(p + 4);
            split8(v, wreg[2 * c], wreg[2 * c + 1]);
        }
        #pragma unroll
        for (int c = 0; c < 8; ++c) {
            const float* p = Whh1 + (size_t)(rb + col) * HH + (w4 * 256 + c * 32 + kg * 8);
            float v[8];
            *(float4*)v       = *(const float4*)p;
            *(float4*)(v + 4) = *(const float4*)(p + 4);
            split8(v, wreg[16 + 2 * c], wreg[17 + 2 * c]);
        }
    }

    // ---- epilogue role constants ----
    const int side = tid >> 8;        // 0: store L0 tile, 1: store L1 tile
    const int u    = tid & 255;
    const int eb   = u & 15;          // batch sub (D-row)
    const int ekk  = u >> 4;          // weight-row sub (D-col)
    const float bsum = (side == 0) ? (bih0[rb + ekk] + bhh0[rb + ekk])
                                   : (bih1[rb + ekk] + bhh1[rb + ekk]);
    const int Rk   = rb + ekk;        // this h element's global k index
    const size_t eoff = (size_t)(Rk >> 5) * 2048
                      + (size_t)(eb + (((Rk & 31) >> 3) << 4)) * 32
                      + (size_t)(Rk & 7) * 2;

    unsigned gen_target = 0;

    for (int t = 0; t <= TT; ++t) {
        f32x4 acc0 = {0.f, 0.f, 0.f, 0.f};
        f32x4 acc1 = {0.f, 0.f, 0.f, 0.f};

        const char* h1r = h1base + (size_t)((((t - 1) & 1)) * 4 + grp) * 65536;
        const char* h2r = h2base + (size_t)((((t - 2) & 1)) * 4 + grp) * 65536;

        if (w < 4) {
            if (t < TT) {
                const float* xb = x + ((size_t)(b0 + col) * TT + t) * II + (w * 64 + kg * 8);
                float v[8];
                bf8 ahi, alo;
                *(float4*)v       = *(const float4*)xb;
                *(float4*)(v + 4) = *(const float4*)(xb + 4);
                split8(v, ahi, alo);
                acc0 = MFMA(ahi, wreg[0], acc0);
                acc0 = MFMA(ahi, wreg[1], acc0);
                acc0 = MFMA(alo, wreg[0], acc0);
                *(float4*)v       = *(const float4*)(xb + 32);
                *(float4*)(v + 4) = *(const float4*)(xb + 36);
                split8(v, ahi, alo);
                acc1 = MFMA(ahi, wreg[2], acc1);
                acc1 = MFMA(ahi, wreg[3], acc1);
                acc1 = MFMA(alo, wreg[2], acc1);
                if (t > 0) {
                    const char* hb = h1r + (size_t)(w * 8) * 2048 + lane * 32;
                    #pragma unroll
                    for (int c = 0; c < 8; ++c) {
                        bf8 hhi = *(const bf8*)(hb + c * 2048);
                        bf8 hlo = *(const bf8*)(hb + c * 2048 + 16);
                        if (c & 1) {
                            acc1 = MFMA(hhi, wreg[4 + 2 * c], acc1);
                            acc1 = MFMA(hhi, wreg[5 + 2 * c], acc1);
                            acc1 = MFMA(hlo, wreg[4 + 2 * c], acc1);
                        } else {
                            acc0 = MFMA(hhi, wreg[4 + 2 * c], acc0);
                            acc0 = MFMA(hhi, wreg[5 + 2 * c], acc0);
                            acc0 = MFMA(hlo, wreg[4 + 2 * c], acc0);
                        }
                    }
                }
            }
        } else {
            if (t >= 1) {
                const int w4 = w - 4;
                const char* hb = h1r + (size_t)(w4 * 8) * 2048 + lane * 32;
                #pragma unroll
                for (int c = 0; c < 8; ++c) {
                    bf8 hhi = *(const bf8*)(hb + c * 2048);
                    bf8 hlo = *(const bf8*)(hb + c * 2048 + 16);
                    if (c & 1) {
                        acc1 = MFMA(hhi, wreg[2 * c], acc1);
                        acc1 = MFMA(hhi, wreg[2 * c + 1], acc1);
                        acc1 = MFMA(hlo, wreg[2 * c], acc1);
                    } else {
                        acc0 = MFMA(hhi, wreg[2 * c], acc0);
                        acc0 = MFMA(hhi, wreg[2 * c + 1], acc0);
                        acc0 = MFMA(hlo, wreg[2 * c], acc0);
                    }
                }
                if (t >= 2) {
                    const char* hb2 = h2r + (size_t)(w4 * 8) * 2048 + lane * 32;
                    #pragma unroll
                    for (int c = 0; c < 8; ++c) {
                        bf8 hhi = *(const bf8*)(hb2 + c * 2048);
                        bf8 hlo = *(const bf8*)(hb2 + c * 2048 + 16);
                        if (c & 1) {
                            acc1 = MFMA(hhi, wreg[16 + 2 * c], acc1);
                            acc1 = MFMA(hhi, wreg[17 + 2 * c], acc1);
                            acc1 = MFMA(hlo, wreg[16 + 2 * c], acc1);
                        } else {
                            acc0 = MFMA(hhi, wreg[16 + 2 * c], acc0);
                            acc0 = MFMA(hhi, wreg[17 + 2 * c], acc0);
                            acc0 = MFMA(hlo, wreg[16 + 2 * c], acc0);
                        }
                    }
                }
            }
        }

        // ---- write partial tiles: Ps[w][D-row=batch][D-col=wrow] ----
        {
            f32x4 s4 = acc0 + acc1;
            #pragma unroll
            for (int r = 0; r < 4; ++r)
                shmem[(w * 16 + kg * 4 + r) * 17 + col] = s4[r];
        }
        __syncthreads();

        // ---- epilogue: reduce 4 partials, bias, tanh, split, store ----
        {
            const bool doit = (side == 0) ? (t < TT) : (t >= 1);
            if (doit) {
                const int wb = side * 4;
                float s = shmem[((wb + 0) * 16 + eb) * 17 + ekk]
                        + shmem[((wb + 1) * 16 + eb) * 17 + ekk]
                        + shmem[((wb + 2) * 16 + eb) * 17 + ekk]
                        + shmem[((wb + 3) * 16 + eb) * 17 + ekk];
                s += bsum;
                const float val = tanhf(s);
                const unsigned short hi = f2bf(val);
                const float r = val - bf2f(hi);
                const unsigned short lo = f2bf(r);
                char* wp = (side ? (h2base + (size_t)(((t - 1) & 1) * 4 + grp) * 65536)
                                 : (h1base + (size_t)((t & 1) * 4 + grp) * 65536)) + eoff;
                *(unsigned short*)wp = hi;
                *(unsigned short*)(wp + 16) = lo;
            }
        }
        __syncthreads();

        // ---- group barrier (64 WGs) ----
        ++gen_target;
        if (tid == 0) {
            __threadfence();
            unsigned a = __hip_atomic_fetch_add(bar, 1u, __ATOMIC_ACQ_REL,
                                                __HIP_MEMORY_SCOPE_AGENT);
            if (a == 63u) {
                __hip_atomic_store(bar, 0u, __ATOMIC_RELAXED, __HIP_MEMORY_SCOPE_AGENT);
                __hip_atomic_store(gen, gen_target, __ATOMIC_RELEASE,
                                   __HIP_MEMORY_SCOPE_AGENT);
            } else {
                while (__hip_atomic_load(gen, __ATOMIC_ACQUIRE,
                                         __HIP_MEMORY_SCOPE_AGENT) < gen_target)
                    __builtin_amdgcn_s_sleep(1);
            }
        }
        __syncthreads();
    }

    // ---- global barrier (256 WGs) before FC ----
    if (tid == 0) {
        __threadfence();
        unsigned a = __hip_atomic_fetch_add(gbar, 1u, __ATOMIC_ACQ_REL,
                                            __HIP_MEMORY_SCOPE_AGENT);
        if (a == 255u) {
            __hip_atomic_store(ggen, 1u, __ATOMIC_RELEASE, __HIP_MEMORY_SCOPE_AGENT);
        } else {
            while (__hip_atomic_load(ggen, __ATOMIC_ACQUIRE,
                                     __HIP_MEMORY_SCOPE_AGENT) < 1u)
                __builtin_amdgcn_s_sleep(1);
        }
    }
    __syncthreads();

    // ---- FC: block g computes out[:, 2g..2g+1]; h2_511 at parity 1 ----
    float* Wlds = shmem + 2176;
    ((float4*)Wlds)[tid] = ((const float4*)(Wfc + (size_t)(2 * blockIdx.x) * HH))[tid];
    __syncthreads();

    float p0 = 0.f, p1 = 0.f;
    {
        const int b    = lane;
        const int gr   = b >> 4;
        const int bsub = b & 15;
        const char* hb = h2base + (size_t)(1 * 4 + gr) * 65536;
        #pragma unroll 4
        for (int k8 = w * 16; k8 < w * 16 + 16; ++k8) {
            const char* p = hb + (size_t)(k8 >> 2) * 2048
                          + (size_t)(bsub + ((k8 & 3) << 4)) * 32;
            bf8 hi = *(const bf8*)p;
            bf8 lo = *(const bf8*)(p + 16);
            const int kb = k8 * 8;
            #pragma unroll
            for (int j = 0; j < 8; ++j) {
                float f = bf2f((unsigned short)hi[j]) + bf2f((unsigned short)lo[j]);
                p0 += f * Wlds[kb + j];
                p1 += f * Wlds[1024 + kb + j];
            }
        }
    }
    shmem[(w * 64 + lane) * 2 + 0] = p0;
    shmem[(w * 64 + lane) * 2 + 1] = p1;
    __syncthreads();
    if (w < 2) {
        float s = bfc[2 * blockIdx.x + w];
        #pragma unroll
        for (int j = 0; j < 8; ++j) s += shmem[(j * 64 + lane) * 2 + w];
        out[(size_t)lane * OO + 2 * blockIdx.x + w] = s;
    }
}

extern "C" void kernel_launch(void* const* d_in, const int* in_sizes, int n_in,
                              void* d_out, int out_size, void* d_ws, size_t ws_size,
                              hipStream_t stream) {
    const float* x    = (const float*)d_in[0];
    const float* Wih0 = (const float*)d_in[1];
    const float* Whh0 = (const float*)d_in[2];
    const float* bih0 = (const float*)d_in[3];
    const float* bhh0 = (const float*)d_in[4];
    const float* Wih1 = (const float*)d_in[5];
    const float* Whh1 = (const float*)d_in[6];
    const float* bih1 = (const float*)d_in[7];
    const float* bhh1 = (const float*)d_in[8];
    const float* Wfc  = (const float*)d_in[9];
    const float* bfc  = (const float*)d_in[10];
    float* out = (float*)d_out;
    float* ws  = (float*)d_ws;

    // zero barrier state every call (replay-safe)
    hipMemsetAsync(d_ws, 0, 1024, stream);

    void* args[] = { (void*)&x,
                     (void*)&Wih0, (void*)&Whh0, (void*)&bih0, (void*)&bhh0,
                     (void*)&Wih1, (void*)&Whh1, (void*)&bih1, (void*)&bhh1,
                     (void*)&Wfc,  (void*)&bfc,  (void*)&out,  (void*)&ws };
    hipLaunchCooperativeKernel((void*)rnn_mfma, dim3(256), dim3(512),
                               args, 0, stream);
}

// Round 6
// 5524.433 us; speedup vs baseline: 4.0379x; 1.9963x over previous
//
#include <hip/hip_runtime.h>
#include <cmath>

#define BB 64
#define TT 512
#define II 256
#define HH 1024
#define OO 512

typedef short bf8 __attribute__((ext_vector_type(8)));    // 8 bf16 vals
typedef float f32x4 __attribute__((ext_vector_type(4)));

#define MFMA(a, b, c) __builtin_amdgcn_mfma_f32_16x16x32_bf16((a), (b), (c), 0, 0, 0)

__device__ __forceinline__ unsigned short f2bf(float f) {
    unsigned u = __float_as_uint(f);
    return (unsigned short)((u + 0x7fffu + ((u >> 16) & 1u)) >> 16);
}
__device__ __forceinline__ float bf2f(unsigned short h) {
    return __uint_as_float((unsigned)h << 16);
}
__device__ __forceinline__ void split8(const float* v, bf8& hi, bf8& lo) {
#pragma unroll
    for (int j = 0; j < 8; ++j) {
        unsigned short h = f2bf(v[j]);
        float r = v[j] - bf2f(h);
        hi[j] = (short)h;
        lo[j] = (short)f2bf(r);
    }
}

// Coherent (cross-XCD) 16B h load: two relaxed agent-scope u64 atomic loads.
// Relaxed agent atomics compile to global_load/store with sc1 (bypass the
// non-coherent per-XCD L2, served by the always-coherent memory-side L3) and
// need NO cache-maintenance (no wbl2/inv) — the Round-5 killer.
__device__ __forceinline__ bf8 load_h(const void* p) {
    unsigned long long a = __hip_atomic_load((const unsigned long long*)p,
                                             __ATOMIC_RELAXED, __HIP_MEMORY_SCOPE_AGENT);
    unsigned long long b = __hip_atomic_load((const unsigned long long*)((const char*)p + 8),
                                             __ATOMIC_RELAXED, __HIP_MEMORY_SCOPE_AGENT);
    union { unsigned long long q[2]; bf8 v; } u;
    u.q[0] = a; u.q[1] = b;
    return u.v;
}

// h fragment-packed layout per (layer, parity, group): 32 K-chunks x 64 lanes x
// (8 bf16 hi [16B] + 8 bf16 lo [16B]) = 64 KB. Element h[b][k] lives at
// chunk k>>5, lane (b&15) + 16*((k&31)>>3), byte j=(k&7): hi at j*2, lo at j*2+16.
//
// Grid: 256 WGs x 512 thr. group = blockIdx&3 (batches group*16..+15),
// cu = blockIdx>>2 (rows cu*16..+15 of both layers).
// Waves 0-3: L0 tile (x K-slice 64 + h1 K-slice 256 each).
// Waves 4-7: L1 tile (h1 K-slice 256 + h2 K-slice 256 each).
__global__ __launch_bounds__(512, 2) void rnn_mfma(
    const float* __restrict__ x,
    const float* __restrict__ Wih0, const float* __restrict__ Whh0,
    const float* __restrict__ bih0, const float* __restrict__ bhh0,
    const float* __restrict__ Wih1, const float* __restrict__ Whh1,
    const float* __restrict__ bih1, const float* __restrict__ bhh1,
    const float* __restrict__ Wfc,  const float* __restrict__ bfc,
    float* __restrict__ out, float* __restrict__ ws)
{
    const int tid  = threadIdx.x;
    const int w    = tid >> 6;      // wave 0..7
    const int lane = tid & 63;
    const int col  = lane & 15;     // mfma row/col index within fragment
    const int kg   = lane >> 4;     // k-group 0..3
    const int grp  = blockIdx.x & 3;
    const int cu   = blockIdx.x >> 2;
    const int rb   = cu * 16;       // row block
    const int b0   = grp * 16;      // batch block

    __shared__ float shmem[4224];   // Ps [8][16][17] = 2176 | Wlds 2048

    char* wsB = (char*)ws;
    unsigned* flags = (unsigned*)wsB;            // [4 groups][64 WGs] u32
    char* h1base = wsB + 4096;
    char* h2base = h1base + 8 * 65536;

    // ---- preload weight B-fragments into registers (once) ----
    bf8 wreg[32];
    if (w < 4) {
        #pragma unroll
        for (int c = 0; c < 2; ++c) {
            const float* p = Wih0 + (size_t)(rb + col) * II + (w * 64 + c * 32 + kg * 8);
            float v[8];
            *(float4*)v       = *(const float4*)p;
            *(float4*)(v + 4) = *(const float4*)(p + 4);
            split8(v, wreg[2 * c], wreg[2 * c + 1]);
        }
        #pragma unroll
        for (int c = 0; c < 8; ++c) {
            const float* p = Whh0 + (size_t)(rb + col) * HH + (w * 256 + c * 32 + kg * 8);
            float v[8];
            *(float4*)v       = *(const float4*)p;
            *(float4*)(v + 4) = *(const float4*)(p + 4);
            split8(v, wreg[4 + 2 * c], wreg[5 + 2 * c]);
        }
    } else {
        const int w4 = w - 4;
        #pragma unroll
        for (int c = 0; c < 8; ++c) {
            const float* p = Wih1 + (size_t)(rb + col) * HH + (w4 * 256 + c * 32 + kg * 8);
            float v[8];
            *(float4*)v       = *(const float4*)p;
            *(float4*)(v + 4) = *(const float4*)(p + 4);
            split8(v, wreg[2 * c], wreg[2 * c + 1]);
        }
        #pragma unroll
        for (int c = 0; c < 8; ++c) {
            const float* p = Whh1 + (size_t)(rb + col) * HH + (w4 * 256 + c * 32 + kg * 8);
            float v[8];
            *(float4*)v       = *(const float4*)p;
            *(float4*)(v + 4) = *(const float4*)(p + 4);
            split8(v, wreg[16 + 2 * c], wreg[17 + 2 * c]);
        }
    }

    // ---- epilogue role constants ----
    const int side = tid >> 8;        // 0: store L0 tile, 1: store L1 tile
    const int u    = tid & 255;
    const int eb   = u & 15;          // batch sub (D-row)
    const int ekk  = u >> 4;          // weight-row sub (D-col)
    const float bsum = (side == 0) ? (bih0[rb + ekk] + bhh0[rb + ekk])
                                   : (bih1[rb + ekk] + bhh1[rb + ekk]);
    const int Rk   = rb + ekk;        // this h element's global k index
    const size_t eoff = (size_t)(Rk >> 5) * 2048
                      + (size_t)(eb + (((Rk & 31) >> 3) << 4)) * 32
                      + (size_t)(Rk & 7) * 2;

    for (int t = 0; t <= TT; ++t) {
        f32x4 acc0 = {0.f, 0.f, 0.f, 0.f};
        f32x4 acc1 = {0.f, 0.f, 0.f, 0.f};

        const char* h1r = h1base + (size_t)((((t - 1) & 1)) * 4 + grp) * 65536;
        const char* h2r = h2base + (size_t)((((t - 2) & 1)) * 4 + grp) * 65536;

        if (w < 4) {
            if (t < TT) {
                const float* xb = x + ((size_t)(b0 + col) * TT + t) * II + (w * 64 + kg * 8);
                float v[8];
                bf8 ahi, alo;
                *(float4*)v       = *(const float4*)xb;
                *(float4*)(v + 4) = *(const float4*)(xb + 4);
                split8(v, ahi, alo);
                acc0 = MFMA(ahi, wreg[0], acc0);
                acc0 = MFMA(ahi, wreg[1], acc0);
                acc0 = MFMA(alo, wreg[0], acc0);
                *(float4*)v       = *(const float4*)(xb + 32);
                *(float4*)(v + 4) = *(const float4*)(xb + 36);
                split8(v, ahi, alo);
                acc1 = MFMA(ahi, wreg[2], acc1);
                acc1 = MFMA(ahi, wreg[3], acc1);
                acc1 = MFMA(alo, wreg[2], acc1);
                if (t > 0) {
                    const char* hb = h1r + (size_t)(w * 8) * 2048 + lane * 32;
                    #pragma unroll
                    for (int c = 0; c < 8; ++c) {
                        bf8 hhi = load_h(hb + c * 2048);
                        bf8 hlo = load_h(hb + c * 2048 + 16);
                        if (c & 1) {
                            acc1 = MFMA(hhi, wreg[4 + 2 * c], acc1);
                            acc1 = MFMA(hhi, wreg[5 + 2 * c], acc1);
                            acc1 = MFMA(hlo, wreg[4 + 2 * c], acc1);
                        } else {
                            acc0 = MFMA(hhi, wreg[4 + 2 * c], acc0);
                            acc0 = MFMA(hhi, wreg[5 + 2 * c], acc0);
                            acc0 = MFMA(hlo, wreg[4 + 2 * c], acc0);
                        }
                    }
                }
            }
        } else {
            if (t >= 1) {
                const int w4 = w - 4;
                const char* hb = h1r + (size_t)(w4 * 8) * 2048 + lane * 32;
                #pragma unroll
                for (int c = 0; c < 8; ++c) {
                    bf8 hhi = load_h(hb + c * 2048);
                    bf8 hlo = load_h(hb + c * 2048 + 16);
                    if (c & 1) {
                        acc1 = MFMA(hhi, wreg[2 * c], acc1);
                        acc1 = MFMA(hhi, wreg[2 * c + 1], acc1);
                        acc1 = MFMA(hlo, wreg[2 * c], acc1);
                    } else {
                        acc0 = MFMA(hhi, wreg[2 * c], acc0);
                        acc0 = MFMA(hhi, wreg[2 * c + 1], acc0);
                        acc0 = MFMA(hlo, wreg[2 * c], acc0);
                    }
                }
                if (t >= 2) {
                    const char* hb2 = h2r + (size_t)(w4 * 8) * 2048 + lane * 32;
                    #pragma unroll
                    for (int c = 0; c < 8; ++c) {
                        bf8 hhi = load_h(hb2 + c * 2048);
                        bf8 hlo = load_h(hb2 + c * 2048 + 16);
                        if (c & 1) {
                            acc1 = MFMA(hhi, wreg[16 + 2 * c], acc1);
                            acc1 = MFMA(hhi, wreg[17 + 2 * c], acc1);
                            acc1 = MFMA(hlo, wreg[16 + 2 * c], acc1);
                        } else {
                            acc0 = MFMA(hhi, wreg[16 + 2 * c], acc0);
                            acc0 = MFMA(hhi, wreg[17 + 2 * c], acc0);
                            acc0 = MFMA(hlo, wreg[16 + 2 * c], acc0);
                        }
                    }
                }
            }
        }

        // ---- write partial tiles: Ps[w][D-row=batch][D-col=wrow] ----
        {
            f32x4 s4 = acc0 + acc1;
            #pragma unroll
            for (int r = 0; r < 4; ++r)
                shmem[(w * 16 + kg * 4 + r) * 17 + col] = s4[r];
        }
        __syncthreads();

        // ---- epilogue: reduce 4 partials, bias, tanh, split, coherent store ----
        {
            const bool doit = (side == 0) ? (t < TT) : (t >= 1);
            if (doit) {
                const int wb = side * 4;
                float s = shmem[((wb + 0) * 16 + eb) * 17 + ekk]
                        + shmem[((wb + 1) * 16 + eb) * 17 + ekk]
                        + shmem[((wb + 2) * 16 + eb) * 17 + ekk]
                        + shmem[((wb + 3) * 16 + eb) * 17 + ekk];
                s += bsum;
                const float val = tanhf(s);
                const unsigned short hi = f2bf(val);
                const float r = val - bf2f(hi);
                const unsigned short lo = f2bf(r);
                char* wp = (side ? (h2base + (size_t)(((t - 1) & 1) * 4 + grp) * 65536)
                                 : (h1base + (size_t)((t & 1) * 4 + grp) * 65536)) + eoff;
                __hip_atomic_store((unsigned short*)wp, hi,
                                   __ATOMIC_RELAXED, __HIP_MEMORY_SCOPE_AGENT);
                __hip_atomic_store((unsigned short*)(wp + 16), lo,
                                   __ATOMIC_RELAXED, __HIP_MEMORY_SCOPE_AGENT);
            }
        }
        // drain this thread's h stores to the coherent point before the flag
        asm volatile("s_waitcnt vmcnt(0)" ::: "memory");
        __syncthreads();   // all waves' stores drained once every thread is here

        // ---- flag-array barrier: publish step completion, poll 64 group flags ----
        {
            const unsigned target = (unsigned)(t + 1);
            if (tid == 0)
                __hip_atomic_store(&flags[grp * 64 + cu], target,
                                   __ATOMIC_RELAXED, __HIP_MEMORY_SCOPE_AGENT);
            const unsigned* fb = &flags[grp * 64];
            for (;;) {
                unsigned f = __hip_atomic_load(&fb[lane], __ATOMIC_RELAXED,
                                               __HIP_MEMORY_SCOPE_AGENT);
                if (__all(f >= target)) break;
                __builtin_amdgcn_s_sleep(2);
            }
        }
    }

    // ---- wait for ALL 256 WGs (FC mixes all 4 groups' h2) ----
    if (tid < 256) {
        while (__hip_atomic_load(&flags[tid], __ATOMIC_RELAXED,
                                 __HIP_MEMORY_SCOPE_AGENT) < (unsigned)(TT + 1))
            __builtin_amdgcn_s_sleep(2);
    }
    __syncthreads();

    // ---- FC: block g computes out[:, 2g..2g+1]; h2_511 at parity 1 ----
    float* Wlds = shmem + 2176;
    ((float4*)Wlds)[tid] = ((const float4*)(Wfc + (size_t)(2 * blockIdx.x) * HH))[tid];
    __syncthreads();

    float p0 = 0.f, p1 = 0.f;
    {
        const int b    = lane;
        const int gr   = b >> 4;
        const int bsub = b & 15;
        const char* hb = h2base + (size_t)(1 * 4 + gr) * 65536;
        #pragma unroll 4
        for (int k8 = w * 16; k8 < w * 16 + 16; ++k8) {
            const char* p = hb + (size_t)(k8 >> 2) * 2048
                          + (size_t)(bsub + ((k8 & 3) << 4)) * 32;
            bf8 hi = load_h(p);
            bf8 lo = load_h(p + 16);
            const int kb = k8 * 8;
            #pragma unroll
            for (int j = 0; j < 8; ++j) {
                float f = bf2f((unsigned short)hi[j]) + bf2f((unsigned short)lo[j]);
                p0 += f * Wlds[kb + j];
                p1 += f * Wlds[1024 + kb + j];
            }
        }
    }
    __syncthreads();
    shmem[(w * 64 + lane) * 2 + 0] = p0;
    shmem[(w * 64 + lane) * 2 + 1] = p1;
    __syncthreads();
    if (w < 2) {
        float s = bfc[2 * blockIdx.x + w];
        #pragma unroll
        for (int j = 0; j < 8; ++j) s += shmem[(j * 64 + lane) * 2 + w];
        out[(size_t)lane * OO + 2 * blockIdx.x + w] = s;
    }
}

extern "C" void kernel_launch(void* const* d_in, const int* in_sizes, int n_in,
                              void* d_out, int out_size, void* d_ws, size_t ws_size,
                              hipStream_t stream) {
    const float* x    = (const float*)d_in[0];
    const float* Wih0 = (const float*)d_in[1];
    const float* Whh0 = (const float*)d_in[2];
    const float* bih0 = (const float*)d_in[3];
    const float* bhh0 = (const float*)d_in[4];
    const float* Wih1 = (const float*)d_in[5];
    const float* Whh1 = (const float*)d_in[6];
    const float* bih1 = (const float*)d_in[7];
    const float* bhh1 = (const float*)d_in[8];
    const float* Wfc  = (const float*)d_in[9];
    const float* bfc  = (const float*)d_in[10];
    float* out = (float*)d_out;
    float* ws  = (float*)d_ws;

    // zero flag region every call (replay-safe)
    hipMemsetAsync(d_ws, 0, 4096, stream);

    void* args[] = { (void*)&x,
                     (void*)&Wih0, (void*)&Whh0, (void*)&bih0, (void*)&bhh0,
                     (void*)&Wih1, (void*)&Whh1, (void*)&bih1, (void*)&bhh1,
                     (void*)&Wfc,  (void*)&bfc,  (void*)&out,  (void*)&ws };
    hipLaunchCooperativeKernel((void*)rnn_mfma, dim3(256), dim3(512),
                               args, 0, stream);
}

// Round 8
// 5165.702 us; speedup vs baseline: 4.3183x; 1.0694x over previous
//
#include <hip/hip_runtime.h>
#include <cmath>

#define BB 64
#define TT 512
#define II 256
#define HH 1024
#define OO 512

typedef short bf8 __attribute__((ext_vector_type(8)));    // 8 bf16 vals
typedef float f32x4 __attribute__((ext_vector_type(4)));

#define MFMA(a, b, c) __builtin_amdgcn_mfma_f32_16x16x32_bf16((a), (b), (c), 0, 0, 0)

__device__ __forceinline__ unsigned short f2bf(float f) {
    unsigned u = __float_as_uint(f);
    return (unsigned short)((u + 0x7fffu + ((u >> 16) & 1u)) >> 16);
}
__device__ __forceinline__ float bf2f(unsigned short h) {
    return __uint_as_float((unsigned)h << 16);
}
__device__ __forceinline__ void split8(const float* v, bf8& hi, bf8& lo) {
#pragma unroll
    for (int j = 0; j < 8; ++j) {
        unsigned short h = f2bf(v[j]);
        float r = v[j] - bf2f(h);
        hi[j] = (short)h;
        lo[j] = (short)f2bf(r);
    }
}

// L3-coherent 16B load (sc1 path) — proven in Round 6.
__device__ __forceinline__ bf8 load_h(const void* p) {
    unsigned long long a = __hip_atomic_load((const unsigned long long*)p,
                                             __ATOMIC_RELAXED, __HIP_MEMORY_SCOPE_AGENT);
    unsigned long long b = __hip_atomic_load((const unsigned long long*)((const char*)p + 8),
                                             __ATOMIC_RELAXED, __HIP_MEMORY_SCOPE_AGENT);
    union { unsigned long long q[2]; bf8 v; } u;
    u.q[0] = a; u.q[1] = b;
    return u.v;
}

// h fragment-packed layout per (layer, parity, group): 32 K-chunks x 64 lanes x
// (8 bf16 hi [16B] + 8 bf16 lo [16B]) = 64 KB. Element h[b][k] lives at
// chunk k>>5, lane (b&15) + 16*((k&31)>>3), byte j=(k&7): hi at j*2, lo at j*2+16.
//
// Grid: 256 WGs x 512 thr. group = blockIdx&3 (batches group*16..+15),
// cu = blockIdx>>2 (rows cu*16..+15 of both layers).
// Waves 0-3: L0 tile (x K-slice 64 + h1 K-slice 256 each).
// Waves 4-7: L1 tile (h1 K-slice 256 + h2 K-slice 256 each).
// Flags: one per WG at 16B stride (index grp*64+cu), stored/polled via
// relaxed agent-scope atomics (L3, placement-independent). Wave 0 polls.
__global__ __launch_bounds__(512, 2) void rnn_mfma(
    const float* __restrict__ x,
    const float* __restrict__ Wih0, const float* __restrict__ Whh0,
    const float* __restrict__ bih0, const float* __restrict__ bhh0,
    const float* __restrict__ Wih1, const float* __restrict__ Whh1,
    const float* __restrict__ bih1, const float* __restrict__ bhh1,
    const float* __restrict__ Wfc,  const float* __restrict__ bfc,
    float* __restrict__ out, float* __restrict__ ws)
{
    const int tid  = threadIdx.x;
    const int w    = tid >> 6;      // wave 0..7
    const int lane = tid & 63;
    const int col  = lane & 15;     // mfma row/col index within fragment
    const int kg   = lane >> 4;     // k-group 0..3
    const int grp  = blockIdx.x & 3;
    const int cu   = blockIdx.x >> 2;
    const int rb   = cu * 16;       // row block
    const int b0   = grp * 16;      // batch block

    __shared__ float shmem[4224];   // Ps [8][16][17] = 2176 | Wlds 2048

    char* wsB = (char*)ws;
    // flag i (i = grp*64+cu, 0..255) at wsB + i*16 (16B spread, 4KB total)
    char* h1base = wsB + 4096;
    char* h2base = h1base + 8 * 65536;

    // ---- preload weight B-fragments into registers (once) ----
    bf8 wreg[32];
    if (w < 4) {
        #pragma unroll
        for (int c = 0; c < 2; ++c) {
            const float* p = Wih0 + (size_t)(rb + col) * II + (w * 64 + c * 32 + kg * 8);
            float v[8];
            *(float4*)v       = *(const float4*)p;
            *(float4*)(v + 4) = *(const float4*)(p + 4);
            split8(v, wreg[2 * c], wreg[2 * c + 1]);
        }
        #pragma unroll
        for (int c = 0; c < 8; ++c) {
            const float* p = Whh0 + (size_t)(rb + col) * HH + (w * 256 + c * 32 + kg * 8);
            float v[8];
            *(float4*)v       = *(const float4*)p;
            *(float4*)(v + 4) = *(const float4*)(p + 4);
            split8(v, wreg[4 + 2 * c], wreg[5 + 2 * c]);
        }
    } else {
        const int w4 = w - 4;
        #pragma unroll
        for (int c = 0; c < 8; ++c) {
            const float* p = Wih1 + (size_t)(rb + col) * HH + (w4 * 256 + c * 32 + kg * 8);
            float v[8];
            *(float4*)v       = *(const float4*)p;
            *(float4*)(v + 4) = *(const float4*)(p + 4);
            split8(v, wreg[2 * c], wreg[2 * c + 1]);
        }
        #pragma unroll
        for (int c = 0; c < 8; ++c) {
            const float* p = Whh1 + (size_t)(rb + col) * HH + (w4 * 256 + c * 32 + kg * 8);
            float v[8];
            *(float4*)v       = *(const float4*)p;
            *(float4*)(v + 4) = *(const float4*)(p + 4);
            split8(v, wreg[16 + 2 * c], wreg[17 + 2 * c]);
        }
    }

    // ---- epilogue role constants ----
    const int side = tid >> 8;        // 0: store L0 tile, 1: store L1 tile
    const int u    = tid & 255;
    const int eb   = u & 15;          // batch sub (D-row)
    const int ekk  = u >> 4;          // weight-row sub (D-col)
    const float bsum = (side == 0) ? (bih0[rb + ekk] + bhh0[rb + ekk])
                                   : (bih1[rb + ekk] + bhh1[rb + ekk]);
    const int Rk   = rb + ekk;        // this h element's global k index
    const size_t eoff = (size_t)(Rk >> 5) * 2048
                      + (size_t)(eb + (((Rk & 31) >> 3) << 4)) * 32
                      + (size_t)(Rk & 7) * 2;

    for (int t = 0; t <= TT; ++t) {
        f32x4 acc0 = {0.f, 0.f, 0.f, 0.f};
        f32x4 acc1 = {0.f, 0.f, 0.f, 0.f};

        const char* h1r = h1base + (size_t)((((t - 1) & 1)) * 4 + grp) * 65536;
        const char* h2r = h2base + (size_t)((((t - 2) & 1)) * 4 + grp) * 65536;

        if (w < 4) {
            if (t < TT) {
                const float* xb = x + ((size_t)(b0 + col) * TT + t) * II + (w * 64 + kg * 8);
                float v[8];
                bf8 ahi, alo;
                *(float4*)v       = *(const float4*)xb;
                *(float4*)(v + 4) = *(const float4*)(xb + 4);
                split8(v, ahi, alo);
                acc0 = MFMA(ahi, wreg[0], acc0);
                acc0 = MFMA(ahi, wreg[1], acc0);
                acc0 = MFMA(alo, wreg[0], acc0);
                *(float4*)v       = *(const float4*)(xb + 32);
                *(float4*)(v + 4) = *(const float4*)(xb + 36);
                split8(v, ahi, alo);
                acc1 = MFMA(ahi, wreg[2], acc1);
                acc1 = MFMA(ahi, wreg[3], acc1);
                acc1 = MFMA(alo, wreg[2], acc1);
                if (t > 0) {
                    const char* hb = h1r + (size_t)(w * 8) * 2048 + lane * 32;
                    #pragma unroll
                    for (int c = 0; c < 8; ++c) {
                        bf8 hhi = load_h(hb + c * 2048);
                        bf8 hlo = load_h(hb + c * 2048 + 16);
                        if (c & 1) {
                            acc1 = MFMA(hhi, wreg[4 + 2 * c], acc1);
                            acc1 = MFMA(hhi, wreg[5 + 2 * c], acc1);
                            acc1 = MFMA(hlo, wreg[4 + 2 * c], acc1);
                        } else {
                            acc0 = MFMA(hhi, wreg[4 + 2 * c], acc0);
                            acc0 = MFMA(hhi, wreg[5 + 2 * c], acc0);
                            acc0 = MFMA(hlo, wreg[4 + 2 * c], acc0);
                        }
                    }
                }
            }
        } else {
            if (t >= 1) {
                const int w4 = w - 4;
                const char* hb = h1r + (size_t)(w4 * 8) * 2048 + lane * 32;
                #pragma unroll
                for (int c = 0; c < 8; ++c) {
                    bf8 hhi = load_h(hb + c * 2048);
                    bf8 hlo = load_h(hb + c * 2048 + 16);
                    if (c & 1) {
                        acc1 = MFMA(hhi, wreg[2 * c], acc1);
                        acc1 = MFMA(hhi, wreg[2 * c + 1], acc1);
                        acc1 = MFMA(hlo, wreg[2 * c], acc1);
                    } else {
                        acc0 = MFMA(hhi, wreg[2 * c], acc0);
                        acc0 = MFMA(hhi, wreg[2 * c + 1], acc0);
                        acc0 = MFMA(hlo, wreg[2 * c], acc0);
                    }
                }
                if (t >= 2) {
                    const char* hb2 = h2r + (size_t)(w4 * 8) * 2048 + lane * 32;
                    #pragma unroll
                    for (int c = 0; c < 8; ++c) {
                        bf8 hhi = load_h(hb2 + c * 2048);
                        bf8 hlo = load_h(hb2 + c * 2048 + 16);
                        if (c & 1) {
                            acc1 = MFMA(hhi, wreg[16 + 2 * c], acc1);
                            acc1 = MFMA(hhi, wreg[17 + 2 * c], acc1);
                            acc1 = MFMA(hlo, wreg[16 + 2 * c], acc1);
                        } else {
                            acc0 = MFMA(hhi, wreg[16 + 2 * c], acc0);
                            acc0 = MFMA(hhi, wreg[17 + 2 * c], acc0);
                            acc0 = MFMA(hlo, wreg[16 + 2 * c], acc0);
                        }
                    }
                }
            }
        }

        // ---- write partial tiles: Ps[w][D-row=batch][D-col=wrow] ----
        {
            f32x4 s4 = acc0 + acc1;
            #pragma unroll
            for (int r = 0; r < 4; ++r)
                shmem[(w * 16 + kg * 4 + r) * 17 + col] = s4[r];
        }
        __syncthreads();

        // ---- epilogue: reduce 4 partials, bias, tanh, split, coherent store ----
        {
            const bool doit = (side == 0) ? (t < TT) : (t >= 1);
            if (doit) {
                const int wb = side * 4;
                float s = shmem[((wb + 0) * 16 + eb) * 17 + ekk]
                        + shmem[((wb + 1) * 16 + eb) * 17 + ekk]
                        + shmem[((wb + 2) * 16 + eb) * 17 + ekk]
                        + shmem[((wb + 3) * 16 + eb) * 17 + ekk];
                s += bsum;
                const float val = tanhf(s);
                const unsigned short hi = f2bf(val);
                const float r = val - bf2f(hi);
                const unsigned short lo = f2bf(r);
                char* wp = (side ? (h2base + (size_t)(((t - 1) & 1) * 4 + grp) * 65536)
                                 : (h1base + (size_t)((t & 1) * 4 + grp) * 65536)) + eoff;
                __hip_atomic_store((unsigned short*)wp, hi,
                                   __ATOMIC_RELAXED, __HIP_MEMORY_SCOPE_AGENT);
                __hip_atomic_store((unsigned short*)(wp + 16), lo,
                                   __ATOMIC_RELAXED, __HIP_MEMORY_SCOPE_AGENT);
            }
        }
        // drain this thread's h stores to the coherent point before the flag
        asm volatile("s_waitcnt vmcnt(0)" ::: "memory");
        __syncthreads();   // all waves' stores drained once every thread is here

        // ---- barrier: tid0 publishes, wave 0 polls the group's 64 flags ----
        {
            const unsigned target = (unsigned)(t + 1);
            if (tid == 0)
                __hip_atomic_store((unsigned*)(wsB + (size_t)(grp * 64 + cu) * 16),
                                   target, __ATOMIC_RELAXED, __HIP_MEMORY_SCOPE_AGENT);
            if (w == 0) {
                const char* fb = wsB + (size_t)grp * 1024 + (size_t)lane * 16;
                for (;;) {
                    unsigned f = __hip_atomic_load((const unsigned*)fb, __ATOMIC_RELAXED,
                                                   __HIP_MEMORY_SCOPE_AGENT);
                    if (__all(f >= target)) break;
                    __builtin_amdgcn_s_sleep(2);
                }
            }
            __syncthreads();
        }
    }

    // ---- wait for ALL 256 WGs (FC mixes all 4 groups' h2) ----
    if (tid < 256) {
        while (__hip_atomic_load((const unsigned*)(wsB + (size_t)tid * 16),
                                 __ATOMIC_RELAXED, __HIP_MEMORY_SCOPE_AGENT)
               < (unsigned)(TT + 1))
            __builtin_amdgcn_s_sleep(2);
    }
    __syncthreads();

    // ---- FC: block g computes out[:, 2g..2g+1]; h2_511 at parity 1 ----
    float* Wlds = shmem + 2176;
    ((float4*)Wlds)[tid] = ((const float4*)(Wfc + (size_t)(2 * blockIdx.x) * HH))[tid];
    __syncthreads();

    float p0 = 0.f, p1 = 0.f;
    {
        const int b    = lane;
        const int gr   = b >> 4;
        const int bsub = b & 15;
        const char* hb = h2base + (size_t)(1 * 4 + gr) * 65536;
        #pragma unroll 4
        for (int k8 = w * 16; k8 < w * 16 + 16; ++k8) {
            const char* p = hb + (size_t)(k8 >> 2) * 2048
                          + (size_t)(bsub + ((k8 & 3) << 4)) * 32;
            bf8 hi = load_h(p);
            bf8 lo = load_h(p + 16);
            const int kb = k8 * 8;
            #pragma unroll
            for (int j = 0; j < 8; ++j) {
                float f = bf2f((unsigned short)hi[j]) + bf2f((unsigned short)lo[j]);
                p0 += f * Wlds[kb + j];
                p1 += f * Wlds[1024 + kb + j];
            }
        }
    }
    __syncthreads();
    shmem[(w * 64 + lane) * 2 + 0] = p0;
    shmem[(w * 64 + lane) * 2 + 1] = p1;
    __syncthreads();
    if (w < 2) {
        float s = bfc[2 * blockIdx.x + w];
        #pragma unroll
        for (int j = 0; j < 8; ++j) s += shmem[(j * 64 + lane) * 2 + w];
        out[(size_t)lane * OO + 2 * blockIdx.x + w] = s;
    }
}

extern "C" void kernel_launch(void* const* d_in, const int* in_sizes, int n_in,
                              void* d_out, int out_size, void* d_ws, size_t ws_size,
                              hipStream_t stream) {
    const float* x    = (const float*)d_in[0];
    const float* Wih0 = (const float*)d_in[1];
    const float* Whh0 = (const float*)d_in[2];
    const float* bih0 = (const float*)d_in[3];
    const float* bhh0 = (const float*)d_in[4];
    const float* Wih1 = (const float*)d_in[5];
    const float* Whh1 = (const float*)d_in[6];
    const float* bih1 = (const float*)d_in[7];
    const float* bhh1 = (const float*)d_in[8];
    const float* Wfc  = (const float*)d_in[9];
    const float* bfc  = (const float*)d_in[10];
    float* out = (float*)d_out;
    float* ws  = (float*)d_ws;

    // zero flag region every call (replay-safe)
    hipMemsetAsync(d_ws, 0, 4096, stream);

    void* args[] = { (void*)&x,
                     (void*)&Wih0, (void*)&Whh0, (void*)&bih0, (void*)&bhh0,
                     (void*)&Wih1, (void*)&Whh1, (void*)&bih1, (void*)&bhh1,
                     (void*)&Wfc,  (void*)&bfc,  (void*)&out,  (void*)&ws };
    hipLaunchCooperativeKernel((void*)rnn_mfma, dim3(256), dim3(512),
                               args, 0, stream);
}